// Round 3
// baseline (229.316 us; speedup 1.0000x reference)
//
#include <hip/hip_runtime.h>
#include <stdint.h>

typedef __bf16 bf16x8 __attribute__((ext_vector_type(8)));
typedef float  f32x4  __attribute__((ext_vector_type(4)));

#define NB   32
#define CI   128
#define HH   56
#define WW   56
#define CO   256
#define HP   58          // 56 + 2 halo
#define HW   (HH*WW)     // 3136
#define MTOT (NB*HW)     // 100352
#define KTOT 1152        // 9*128, k = (r*3+s)*128 + c

#define XT_ELEMS ((size_t)NB*HP*HP*CI)   // 13,778,944
#define XT_BYTES (XT_ELEMS*2)            // 27,557,888 (16B-aligned)

// ---------- fused prep: xpose (blocks 0..1791) | wxform (1792..2943) | halo (2944..3399) ----------
#define XPOSE_BLKS 1792                  // NB*HH
#define WX_BLKS    1152                  // CO*KTOT/256
#define HALO_BLKS  456                   // NB*228*16/256
__global__ void prep_kernel(const float* __restrict__ x, const float* __restrict__ wg,
                            __bf16* __restrict__ xt, __bf16* __restrict__ wt) {
  __shared__ float tile[CI][57];         // xpose only; +1 row pad breaks pow-2 strides
  int bid = blockIdx.x;
  int t = threadIdx.x;
  if (bid < XPOSE_BLKS) {
    // x: NCHW f32 -> padded NHWC bf16, one (n,h) slice per block
    int n = bid / HH, h = bid % HH;
    const float* src = x + (size_t)n * CI * HW + (size_t)h * WW;
    for (int idx = t; idx < CI * 14; idx += 256) {
      int c = idx / 14, w4 = idx - c * 14;
      float4 v = *(const float4*)(src + (size_t)c * HW + w4 * 4);
      tile[c][w4 * 4 + 0] = v.x;
      tile[c][w4 * 4 + 1] = v.y;
      tile[c][w4 * 4 + 2] = v.z;
      tile[c][w4 * 4 + 3] = v.w;
    }
    __syncthreads();
    __bf16* dst = xt + ((size_t)(n * HP + h + 1) * HP + 1) * CI;
    for (int idx = t; idx < WW * 16; idx += 256) {
      int w = idx >> 4, c8 = (idx & 15) * 8;
      bf16x8 v;
      for (int k = 0; k < 8; ++k) v[k] = (__bf16)tile[c8 + k][w];
      *(bf16x8*)(dst + (size_t)w * CI + c8) = v;
    }
  } else if (bid < XPOSE_BLKS + WX_BLKS) {
    // weight: OIHW f32 -> [CO][KTOT] bf16, k=(r*3+s)*128+c
    int id = (bid - XPOSE_BLKS) * 256 + t;
    int o = id / KTOT;
    int k = id - o * KTOT;
    int rs = k >> 7, c = k & 127;
    wt[id] = (__bf16)wg[(size_t)o * KTOT + c * 9 + rs];
  } else {
    // zero the halo ring of xt (1.87 MB): 228 perimeter pixels x 256 B per image
    int id = (bid - XPOSE_BLKS - WX_BLKS) * 256 + t;
    if (id < NB * 228 * 16) {
      int chunk = id & 15;
      int p = (id >> 4) % 228;
      int n = id / (228 * 16);
      int h, w;
      if (p < 58)       { h = 0;           w = p; }
      else if (p < 116) { h = 57;          w = p - 58; }
      else if (p < 172) { h = p - 116 + 1; w = 0; }
      else              { h = p - 172 + 1; w = 57; }
      int4* dst = (int4*)(xt + ((size_t)(n * HP + h) * HP + w) * CI) + chunk;
      *dst = make_int4(0, 0, 0, 0);
    }
  }
}

// ---------- implicit-GEMM conv: single-barrier double-buffered K-loop ----------
#define BM 128
#define BN 128
#define NKIT 36          // KTOT/32

__device__ __forceinline__ void gload_lds16(const __bf16* g, __bf16* l) {
  __builtin_amdgcn_global_load_lds(
      (const __attribute__((address_space(1))) void*)g,
      (__attribute__((address_space(3))) void*)l, 16, 0, 0);
}

__global__ __launch_bounds__(256, 3) void conv_gemm(
    const __bf16* __restrict__ xt, const __bf16* __restrict__ wt,
    const float* __restrict__ bias, float* __restrict__ out) {
  // Double-buffered BK=32 panels: one barrier per iter; the prefetch issued just
  // after barrier k lands during compute k, so barrier k+1's vmcnt(0) drain is
  // mostly pre-satisfied. 32 KB total LDS.
  __shared__ __bf16 Alds[2][BM * 32];
  __shared__ __bf16 Blds[2][BN * 32];
  int t = threadIdx.x;
  int bx = blockIdx.x;
  int nb = bx & 1, mb = bx >> 1;

  // Staging bases: 2 issues x 256 lanes x 16 B = 8 KB (128 rows x 64 B) per matrix.
  size_t baseA[2], baseB[2];
  __bf16* ldsA[2][2];   // [issue][buf]
  __bf16* ldsB[2][2];
  for (int i = 0; i < 2; ++i) {
    int ml = i * 64 + (t >> 2);
    unsigned m = mb * BM + ml;
    unsigned nimg = m / HW;
    unsigned hw = m - nimg * HW;
    unsigned h = hw / WW;
    unsigned w = hw - h * WW;
    baseA[i] = ((size_t)(nimg * HP + h) * HP + w) * CI + (t & 3) * 8;
    baseB[i] = (size_t)(nb * BN + ml) * KTOT + (t & 3) * 8;
    for (int p = 0; p < 2; ++p) {
      ldsA[i][p] = &Alds[p][ml * 32 + (t & 3) * 8];
      ldsB[i][p] = &Blds[p][ml * 32 + (t & 3) * 8];
    }
  }

  int wid = t >> 6, lane = t & 63;
  int wm = (wid >> 1) * 64, wn = (wid & 1) * 64;   // 64x64 quadrant per wave
  int lr = lane & 15, lk = (lane >> 4) * 8;

  f32x4 acc[4][4];
  for (int i = 0; i < 4; ++i)
    for (int j = 0; j < 4; ++j) acc[i][j] = (f32x4){0.f, 0.f, 0.f, 0.f};

  // prologue: stage kt=0 into buf 0
  gload_lds16(xt + baseA[0], ldsA[0][0]);
  gload_lds16(xt + baseA[1], ldsA[1][0]);
  gload_lds16(wt + baseB[0], ldsB[0][0]);
  gload_lds16(wt + baseB[1], ldsB[1][0]);

#pragma unroll 2
  for (int kt = 0; kt < NKIT; ++kt) {
    int cur = kt & 1;
    __syncthreads();          // buf[cur] staged (vmcnt drain) + buf[cur^1] free
    if (kt != NKIT - 1) {
      int kn = kt + 1;
      int rs = kn >> 2;               // (r,s) fixed per 4 K-chunks (128/32)
      int r = (rs * 11) >> 5;         // rs/3 for rs in [0,9)
      int s = rs - 3 * r;
      size_t offA = ((size_t)(r * HP + s)) * CI + (size_t)(kn & 3) * 32;
      size_t offB = (size_t)kn * 32;
      int nxt = cur ^ 1;
      gload_lds16(xt + baseA[0] + offA, ldsA[0][nxt]);
      gload_lds16(xt + baseA[1] + offA, ldsA[1][nxt]);
      gload_lds16(wt + baseB[0] + offB, ldsB[0][nxt]);
      gload_lds16(wt + baseB[1] + offB, ldsB[1][nxt]);
    }
    bf16x8 a[4], b[4];
    for (int i = 0; i < 4; ++i) {
      a[i] = *(const bf16x8*)&Alds[cur][(wm + i * 16 + lr) * 32 + lk];
      b[i] = *(const bf16x8*)&Blds[cur][(wn + i * 16 + lr) * 32 + lk];
    }
    for (int i = 0; i < 4; ++i)
      for (int j = 0; j < 4; ++j)
        acc[i][j] = __builtin_amdgcn_mfma_f32_16x16x32_bf16(a[i], b[j], acc[i][j], 0, 0, 0);
  }

  // Epilogue: C/D layout col(=n)=lane&15, row(=m)=(lane>>4)*4+reg [m89-verified].
  // r2 spans 4 consecutive hw within one image (m0 % 4 == 0, HW % 4 == 0) -> f32x4.
  for (int j = 0; j < 4; ++j) {
    int o = nb * BN + wn + j * 16 + lr;
    float bv = bias[o];
    for (int i = 0; i < 4; ++i) {
      unsigned m0 = mb * BM + wm + i * 16 + (lane >> 4) * 4;
      unsigned nimg = m0 / HW;
      unsigned hw = m0 - nimg * HW;
      f32x4 v = acc[i][j] + bv;
      *(f32x4*)(out + ((size_t)nimg * CO + o) * HW + hw) = v;
    }
  }
}

extern "C" void kernel_launch(void* const* d_in, const int* in_sizes, int n_in,
                              void* d_out, int out_size, void* d_ws, size_t ws_size,
                              hipStream_t stream) {
  const float* x    = (const float*)d_in[0];
  const float* wg   = (const float*)d_in[1];
  const float* bias = (const float*)d_in[2];
  float* out = (float*)d_out;

  __bf16* xt = (__bf16*)d_ws;
  __bf16* wt = (__bf16*)((char*)d_ws + XT_BYTES);

  prep_kernel<<<XPOSE_BLKS + WX_BLKS + HALO_BLKS, 256, 0, stream>>>(x, wg, xt, wt);
  conv_gemm<<<(MTOT / BM) * (CO / BN), 256, 0, stream>>>(xt, wt, bias, out);
}

// Round 4
// 225.239 us; speedup vs baseline: 1.0181x; 1.0181x over previous
//
#include <hip/hip_runtime.h>
#include <stdint.h>

typedef __bf16 bf16x8 __attribute__((ext_vector_type(8)));
typedef float  f32x4  __attribute__((ext_vector_type(4)));

#define NB   32
#define CI   128
#define HH   56
#define WW   56
#define CO   256
#define HP   58          // 56 + 2 halo
#define HW   (HH*WW)     // 3136
#define MTOT (NB*HW)     // 100352
#define KTOT 1152        // 9*128, k = (r*3+s)*128 + c

#define XT_ELEMS ((size_t)NB*HP*HP*CI)   // 13,778,944
#define XT_BYTES (XT_ELEMS*2)            // 27,557,888 (16B-aligned)

// ---------- fused prep: xpose | wshuffle | halo-zero ----------
#define XPOSE_BLKS 1792                  // NB*HH
#define WX_BLKS    1152                  // CO*KTOT/256
#define HALO_BLKS  456                   // NB*228*16/256
__global__ void prep_kernel(const float* __restrict__ x, const float* __restrict__ wg,
                            __bf16* __restrict__ xt, __bf16* __restrict__ wts) {
  __shared__ float tile[CI][57];         // xpose only; +1 row pad breaks pow-2 strides
  int bid = blockIdx.x;
  int t = threadIdx.x;
  if (bid < XPOSE_BLKS) {
    // x: NCHW f32 -> padded NHWC bf16, one (n,h) slice per block
    int n = bid / HH, h = bid % HH;
    const float* src = x + (size_t)n * CI * HW + (size_t)h * WW;
    for (int idx = t; idx < CI * 14; idx += 256) {
      int c = idx / 14, w4 = idx - c * 14;
      float4 v = *(const float4*)(src + (size_t)c * HW + w4 * 4);
      tile[c][w4 * 4 + 0] = v.x;
      tile[c][w4 * 4 + 1] = v.y;
      tile[c][w4 * 4 + 2] = v.z;
      tile[c][w4 * 4 + 3] = v.w;
    }
    __syncthreads();
    __bf16* dst = xt + ((size_t)(n * HP + h + 1) * HP + 1) * CI;
    for (int idx = t; idx < WW * 16; idx += 256) {
      int w = idx >> 4, c8 = (idx & 15) * 8;
      bf16x8 v;
      for (int k = 0; k < 8; ++k) v[k] = (__bf16)tile[c8 + k][w];
      *(bf16x8*)(dst + (size_t)w * CI + c8) = v;
    }
  } else if (bid < XPOSE_BLKS + WX_BLKS) {
    // weight -> MFMA-fragment-shuffled layout (flatmm-style):
    // wts[((kc*16 + n16)*64 + lane)*8 + e] = B[n16*16 + (lane&15)][kc*32 + (lane>>4)*8 + e]
    // where B[o][k] with k=(r*3+s)*128+c, source OIHW wg[o*1152 + c*9 + rs].
    int id = (bid - XPOSE_BLKS) * 256 + t;   // element index into wts
    int e   = id & 7;
    int ln  = (id >> 3) & 63;
    int n16 = (id >> 9) & 15;
    int kc  = id >> 13;                      // 0..35
    int o = n16 * 16 + (ln & 15);
    int k = kc * 32 + (ln >> 4) * 8 + e;
    int rs = k >> 7, c = k & 127;
    wts[id] = (__bf16)wg[(size_t)o * KTOT + c * 9 + rs];
  } else {
    // zero the halo ring of xt: 228 perimeter pixels x 256 B per image
    int id = (bid - XPOSE_BLKS - WX_BLKS) * 256 + t;
    if (id < NB * 228 * 16) {
      int chunk = id & 15;
      int p = (id >> 4) % 228;
      int n = id / (228 * 16);
      int h, w;
      if (p < 58)       { h = 0;           w = p; }
      else if (p < 116) { h = 57;          w = p - 58; }
      else if (p < 172) { h = p - 116 + 1; w = 0; }
      else              { h = p - 172 + 1; w = 57; }
      int4* dst = (int4*)(xt + ((size_t)(n * HP + h) * HP + w) * CI) + chunk;
      *dst = make_int4(0, 0, 0, 0);
    }
  }
}

// ---------- implicit-GEMM conv: BK=128 (one 3x3 tap per iter), A-only LDS ----------
#define BM 128

__device__ __forceinline__ void gload_lds16(const __bf16* g, __bf16* l) {
  __builtin_amdgcn_global_load_lds(
      (const __attribute__((address_space(1))) void*)g,
      (__attribute__((address_space(3))) void*)l, 16, 0, 0);
}

__global__ __launch_bounds__(256, 3) void conv_gemm(
    const __bf16* __restrict__ xt, const __bf16* __restrict__ wts,
    const float* __restrict__ bias, float* __restrict__ out) {
  // A-tile only in LDS: 128 rows x 128 k (one tap) = 32 KB, single buffer.
  // XOR-swizzled chunks: logical (m, k8) lives at phys chunk m*16 + (k8 ^ (m&15)),
  // making fragment ds_read_b128 bank-uniform. Swizzle is applied on the GLOBAL
  // source address (lane->LDS slot is pinned by global_load_lds).
  __shared__ __bf16 Alds[BM * 128];
  int t = threadIdx.x;
  int bx = blockIdx.x;
  int nb = bx & 1, mb = bx >> 1;

  // Staging: 8 rounds x 256 lanes x 16 B. Round r, thread t -> phys chunk r*256+t
  // -> logical m = r*16 + (t>>4), k8 = (t&15) ^ (t>>4).
  unsigned k8s = (t & 15) ^ (t >> 4);
  unsigned rowOff[8];
  for (int r = 0; r < 8; ++r) {
    unsigned m = mb * BM + r * 16 + (t >> 4);
    unsigned nimg = m / HW;
    unsigned hw = m - nimg * HW;
    unsigned h = hw / WW;
    unsigned w = hw - h * WW;
    rowOff[r] = ((nimg * HP + h) * HP + w) * CI + k8s * 8;
  }

  int wid = t >> 6, lane = t & 63;
  int wm = (wid >> 1) * 64, wn = (wid & 1) * 64;   // 64x64 quadrant per wave
  int lr = lane & 15, lhi = lane >> 4;
  unsigned n16base = (unsigned)(nb * 128 + wn) >> 4;
  const bf16x8* wfrag = (const bf16x8*)wts;

  f32x4 acc[4][4];
  for (int i = 0; i < 4; ++i)
    for (int j = 0; j < 4; ++j) acc[i][j] = (f32x4){0.f, 0.f, 0.f, 0.f};

  for (int kt = 0; kt < 9; ++kt) {       // one (r,s) tap per iteration
    int r = (kt * 11) >> 5;              // kt/3
    int s = kt - 3 * r;
    unsigned tapOff = (unsigned)(r * HP + s) * CI;
    if (kt) __syncthreads();             // previous compute done before overwrite
#pragma unroll
    for (int rr = 0; rr < 8; ++rr)
      gload_lds16(xt + rowOff[rr] + tapOff, &Alds[rr * 2048 + t * 8]);
    __syncthreads();                     // drain staging
#pragma unroll
    for (int subk = 0; subk < 4; ++subk) {
      unsigned kc = (unsigned)kt * 4 + subk;
      bf16x8 b[4];
      for (int j = 0; j < 4; ++j)
        b[j] = wfrag[(kc * 16 + n16base + j) * 64 + lane];   // coalesced 1 KB/wave, L2-hit
      bf16x8 a[4];
      for (int i = 0; i < 4; ++i) {
        unsigned m = wm + i * 16 + lr;
        unsigned phys = m * 16 + ((subk * 4 + lhi) ^ lr);    // m&15 == lr
        a[i] = *(const bf16x8*)&Alds[phys * 8];
      }
      for (int i = 0; i < 4; ++i)
        for (int j = 0; j < 4; ++j)
          acc[i][j] = __builtin_amdgcn_mfma_f32_16x16x32_bf16(a[i], b[j], acc[i][j], 0, 0, 0);
    }
  }

  // Epilogue: C/D layout col(=n)=lane&15, row(=m)=(lane>>4)*4+reg [m89-verified].
  // r2 spans 4 consecutive hw within one image (m0 % 4 == 0, HW % 4 == 0) -> f32x4.
  for (int j = 0; j < 4; ++j) {
    int o = nb * 128 + wn + j * 16 + lr;
    float bv = bias[o];
    for (int i = 0; i < 4; ++i) {
      unsigned m0 = mb * BM + wm + i * 16 + lhi * 4;
      unsigned nimg = m0 / HW;
      unsigned hw = m0 - nimg * HW;
      f32x4 v = acc[i][j] + bv;
      *(f32x4*)(out + ((size_t)nimg * CO + o) * HW + hw) = v;
    }
  }
}

extern "C" void kernel_launch(void* const* d_in, const int* in_sizes, int n_in,
                              void* d_out, int out_size, void* d_ws, size_t ws_size,
                              hipStream_t stream) {
  const float* x    = (const float*)d_in[0];
  const float* wg   = (const float*)d_in[1];
  const float* bias = (const float*)d_in[2];
  float* out = (float*)d_out;

  __bf16* xt  = (__bf16*)d_ws;
  __bf16* wts = (__bf16*)((char*)d_ws + XT_BYTES);

  prep_kernel<<<XPOSE_BLKS + WX_BLKS + HALO_BLKS, 256, 0, stream>>>(x, wg, xt, wts);
  conv_gemm<<<(MTOT / BM) * (CO / 128), 256, 0, stream>>>(xt, wts, bias, out);
}